// Round 13
// baseline (3309.286 us; speedup 1.0000x reference)
//
#include <hip/hip_runtime.h>

#define HW_ (512 * 512)
#define B_ 8
#define H_ 512
#define W_ 512
#define K_ 32
#define CH_ 16
#define CHPIX_ (HW_ / CH_)  // 16384 pixels per chunk

typedef float float2v __attribute__((ext_vector_type(2)));

// ---------------- compact phase A: per-chunk valid count ----------------
__global__ void k_count(const float* __restrict__ seg, int* __restrict__ chunkCnt) {
  const int blk = blockIdx.x;  // b*CH_ + c
  const int t = threadIdx.x;
  const float4* __restrict__ s4 = (const float4*)(seg + (size_t)blk * CHPIX_) + (size_t)t * 16;
  int cnt = 0;
#pragma unroll
  for (int j = 0; j < 16; ++j) {
    float4 v = s4[j];
    cnt += (v.x >= 0.9f) + (v.y >= 0.9f) + (v.z >= 0.9f) + (v.w >= 0.9f);
  }
  __shared__ int red[256];
  red[t] = cnt;
  __syncthreads();
  for (int off = 128; off > 0; off >>= 1) {
    if (t < off) red[t] += red[t + off];
    __syncthreads();
  }
  if (t == 0) chunkCnt[blk] = red[0];
}

// ---------------- compact phase B: per-batch chunk base offsets ----------------
__global__ void k_scan(const int* __restrict__ chunkCnt, int* __restrict__ chunkBase,
                       int* __restrict__ nvalid, int cap) {
  const int t = threadIdx.x;  // b*CH_ + c
  if (t < B_ * CH_) {
    const int b = t / CH_, c = t % CH_;
    int base = 0;
    for (int q = 0; q < c; ++q) base += chunkCnt[b * CH_ + q];
    chunkBase[t] = base;
    if (c == CH_ - 1) nvalid[b] = min(base + chunkCnt[t], cap);
  }
}

// ---------------- compact phase C: ordered compaction + gather + lanes memset ----------------
__global__ void k_fill(const float* __restrict__ seg, const float* __restrict__ emb,
                       const int* __restrict__ chunkBase, unsigned char* __restrict__ lanes,
                       int* __restrict__ idxC, float* __restrict__ embC, int cap) {
  const int blk = blockIdx.x;  // b*CH_ + c
  const int b = blk / CH_;
  const int t = threadIdx.x;
  const size_t pixbase = (size_t)blk * CHPIX_ + (size_t)t * 64;
  const float4* __restrict__ s4 = (const float4*)(seg + pixbase);

  int cnt = 0;
#pragma unroll
  for (int j = 0; j < 16; ++j) {
    float4 v = s4[j];
    cnt += (v.x >= 0.9f) + (v.y >= 0.9f) + (v.z >= 0.9f) + (v.w >= 0.9f);
  }
  __shared__ int pre[256];
  pre[t] = cnt;
  __syncthreads();
  for (int off = 1; off < 256; off <<= 1) {
    int mine = pre[t];
    int add = (t >= off) ? pre[t - off] : 0;
    __syncthreads();
    pre[t] = mine + add;
    __syncthreads();
  }
  int w = chunkBase[blk] + pre[t] - cnt;

  uint4 z = {0u, 0u, 0u, 0u};
  uint4* lz = (uint4*)(lanes + pixbase);
  lz[0] = z; lz[1] = z; lz[2] = z; lz[3] = z;

  const float* __restrict__ eb = emb + (size_t)b * 8 * HW_;
  const int pixInB = (int)(pixbase - (size_t)b * HW_);
  for (int j = 0; j < 16; ++j) {
    float4 v = s4[j];
    float sv[4] = {v.x, v.y, v.z, v.w};
#pragma unroll
    for (int q = 0; q < 4; ++q) {
      if (sv[q] >= 0.9f && w < cap) {
        const int p = pixInB + j * 4 + q;
        idxC[(size_t)b * cap + w] = p;
        float* dst = embC + ((size_t)b * cap + w) * 8;
#pragma unroll
        for (int dd = 0; dd < 8; ++dd) dst[dd] = eb[(size_t)dd * HW_ + p];
        ++w;
      }
    }
  }
}

// ---------------- sequential clustering: all-VALU decision tail ----------------
// 8 blocks x 1 wave, one batch each. Centers mirrored 4x across rows
// (cl = lane & 31; rows 0,2 = centers 0-15 state mirrored in rows 1,3? no:
//  rows 0,2 hold centers 0-15 and rows 1,3 centers 16-31 -- lanes l and l+32
//  are exact twins). Reduce: 4 in-row DPP-min levels + row_bcast15 level ->
// lanes 16-63 hold the GLOBAL min key in-register (rows 1..3 each combine
// with the previous row; mirrored rows make every such pair cover all 32
// centers). w is then pure VALU: wJoin=(key==mn)?inv:0, join=mn<thr,
// w_pre = join?wJoin:wNew (wNew precomputed off-chain from SALU nact).
// Lanes 0-31 take their twin's w via permlane32_swap (semantics probed once
// in the prologue; per-lane select keeps lanes>=32 untouched). cid/pack/nact
// extraction (readlane + SALU) runs OFF the w-chain in the next step's shadow.

#define TILE_ 32

#if defined(__has_builtin)
#if __has_builtin(__builtin_amdgcn_permlane32_swap)
#define HAVE_PLSWAP 1
#endif
#endif

__device__ __forceinline__ void stage16(const float* g, float* l) {
  __builtin_amdgcn_global_load_lds(
      (const __attribute__((address_space(1))) void*)g,
      (__attribute__((address_space(3))) void*)l, 16, 0, 0);
}

#define RLU(V, L) ((unsigned)__builtin_amdgcn_readlane((int)(V), (L)))
#define PKF(A, B, C) __builtin_elementwise_fma((A), (B), (C))

// J: step 0..31 (pixel J of tile). US: slot used = J%3. LS: slot loaded = (J+2)%3.
#define STEPQ(J, US, LS)                                                             \
  do {                                                                               \
    float2v t01 = C01 - e01_##US;                                                    \
    float2v t23 = C23 - e23_##US;                                                    \
    float2v t45 = C45 - e45_##US;                                                    \
    float2v t67 = C67 - e67_##US;                                                    \
    float2v pA = t01 * t01;                                                          \
    pA = PKF(t23, t23, pA);                                                          \
    float2v pB = t45 * t45;                                                          \
    pB = PKF(t67, t67, pB);                                                          \
    pA = pA + pB;                                                                    \
    float dsq = pA.x + pA.y;                                                         \
    unsigned db = __float_as_uint(dsq);                                              \
    unsigned dbm = db > emptyBits ? db : emptyBits; /* empty center -> inf */        \
    unsigned key = (dbm & 0xFFFFFFE0u) | (unsigned)cl;                               \
    unsigned mn = key, mr;                                                           \
    mr = (unsigned)__builtin_amdgcn_update_dpp(0, (int)mn, 0xB1, 0xF, 0xF, true);    \
    mn = mn < mr ? mn : mr;                                                          \
    mr = (unsigned)__builtin_amdgcn_update_dpp(0, (int)mn, 0x4E, 0xF, 0xF, true);    \
    mn = mn < mr ? mn : mr;                                                          \
    mr = (unsigned)__builtin_amdgcn_update_dpp(0, (int)mn, 0x141, 0xF, 0xF, true);   \
    mn = mn < mr ? mn : mr;                                                          \
    mr = (unsigned)__builtin_amdgcn_update_dpp(0, (int)mn, 0x140, 0xF, 0xF, true);   \
    mn = mn < mr ? mn : mr;                                                          \
    /* level 5: row_bcast15 into rows 1-3 (old=mn keeps row0 benign) */              \
    mr = (unsigned)__builtin_amdgcn_update_dpp((int)mn, (int)mn, 0x142, 0xE, 0xF,    \
                                               false);                               \
    mn = mn < mr ? mn : mr; /* lanes 16-63 now hold the global min */                \
    /* all-VALU w (valid on lanes 16-63) */                                          \
    float wJoin = (key == mn) ? inv : 0.0f;                                          \
    bool join_v = mn < 0x41100000u; /* dsq < 9.0 <=> sqrt(dsq) < 3, exact */         \
    float w_pre = join_v ? wJoin : wNew;                                             \
    float w;                                                                         \
    WSWAP(w, w_pre)                                                                  \
    float2v w2 = {w, w};                                                             \
    C01 = PKF(t01, -w2, C01); /* C -= w*t */                                         \
    C23 = PKF(t23, -w2, C23);                                                        \
    C45 = PKF(t45, -w2, C45);                                                        \
    C67 = PKF(t67, -w2, C67);                                                        \
    bool ownb = w > 0.0f;                                                            \
    cnt = ownb ? cntp1 : cnt;                                                        \
    cntp1 = cnt + 1.0f;                                                              \
    inv = __builtin_amdgcn_rcpf(cntp1);                                              \
    emptyBits = ownb ? 0u : emptyBits;                                               \
    /* OFF-chain scalar decisions: pack, nact, next wNew */                          \
    unsigned s_mv = RLU(mn, 16);                                                     \
    bool join_s = s_mv < 0x41100000u;                                                \
    int nactc = nact < 31 ? nact : 31;                                               \
    int cid = join_s ? (int)(s_mv & 31u) : nactc;                                    \
    nact += join_s ? 0 : 1;                                                          \
    int nactc2 = nact < 31 ? nact : 31;                                              \
    wNew = ((unsigned)cl == (unsigned)nactc2) ? 1.0f : 0.0f;                         \
    pk |= (unsigned long long)(unsigned)(cid + 1) << (((J) & 7) * 8);                \
    if (((J) & 7) == 7) {                                                            \
      if (lane == 0) *(unsigned long long*)(cptr + ((J) & ~7)) = pk;                 \
      pk = 0ULL;                                                                     \
    }                                                                                \
    if ((J) < TILE_ - 2) { /* e-loads for step J+2 (uniform broadcast) */            \
      e01_##LS = ebq[((J) + 2) * 4 + 0];                                             \
      e23_##LS = ebq[((J) + 2) * 4 + 1];                                             \
      e45_##LS = ebq[((J) + 2) * 4 + 2];                                             \
      e67_##LS = ebq[((J) + 2) * 4 + 3];                                             \
    }                                                                                \
  } while (0)

#if HAVE_PLSWAP
// cross-lane fix: lanes 0-31 take w from lanes 32-63 (their exact twins);
// selA (probed in prologue) picks the swap component whose LOW half came
// from the source's HIGH half; lanes >= 32 always keep their own w_pre.
#define WSWAP(W, WPRE)                                                           \
  {                                                                              \
    auto ws_ = __builtin_amdgcn_permlane32_swap(__float_as_uint(WPRE),           \
                                                __float_as_uint(WPRE), false,    \
                                                false);                          \
    float wls_ = selA ? __uint_as_float(ws_[0]) : __uint_as_float(ws_[1]);       \
    W = (lane < 32) ? wls_ : (WPRE);                                             \
  }
#else
#define WSWAP(W, WPRE)                                                           \
  {                                                                              \
    int wb_ = __builtin_amdgcn_ds_bpermute(bpa, (int)__float_as_uint(WPRE));     \
    W = __uint_as_float((unsigned)wb_);                                          \
  }
#endif

__global__ __launch_bounds__(64, 1) void k_cluster(const float* __restrict__ embC,
                                                   const int* __restrict__ nvalid,
                                                   unsigned char* __restrict__ cidArr,
                                                   int cap) {
  __shared__ float lds[512];  // 2 phases x 256 floats (1KB per phase)
  const int b = blockIdx.x;
  const int lane = threadIdx.x;
  const int cl = lane & 31;
  const int n = nvalid[b];
  if (n <= 0) return;
  const int nTiles = (n + TILE_ - 1) / TILE_;

  const float* src = embC + (size_t)b * cap * 8 + lane * 4;
  unsigned char* cidB = cidArr + (size_t)b * HW_;

#if HAVE_PLSWAP
  // probe permlane32_swap semantics once: which component's low half holds
  // the source's high half?  (lane-value probe: want 32 at lane 0)
  bool selA;
  {
    unsigned lv = (unsigned)lane;
    auto pr = __builtin_amdgcn_permlane32_swap(lv, lv, false, false);
    selA = (RLU(pr[0], 0) == 32u);
  }
#else
  const int bpa = ((lane < 32) ? (lane + 32) : lane) * 4;  // twin pull address
#endif

  float2v C01 = {0.f, 0.f}, C23 = C01, C45 = C01, C67 = C01;
  float2v e01_0, e23_0, e45_0, e67_0;
  float2v e01_1, e23_1, e45_1, e67_1;
  float2v e01_2, e23_2, e45_2, e67_2;
  float cnt = 0.f, cntp1 = 1.0f, inv = 1.0f;
  float wNew = (cl == 0) ? 1.0f : 0.0f;  // nact=0 -> first new cluster owner
  unsigned emptyBits = 0x7F800000u;
  int nact = 0;
  unsigned long long pk = 0ULL;

  // prologue: stage tile 0 into phase 0, wait
  stage16(src, lds);
  asm volatile("s_waitcnt vmcnt(0)" ::: "memory");
  __builtin_amdgcn_sched_barrier(0);

  for (int ti = 0; ti < nTiles; ++ti) {
    const bool more = (ti + 1 < nTiles);
    const float2v* ebq = (const float2v*)((const char*)lds + (ti & 1) * 1024);
    unsigned char* cptr = cidB + ti * TILE_;

    // slot prologue: pixels 0,1 of this tile (uniform-broadcast LDS reads)
    e01_0 = ebq[0]; e23_0 = ebq[1]; e45_0 = ebq[2]; e67_0 = ebq[3];
    e01_1 = ebq[4]; e23_1 = ebq[5]; e45_1 = ebq[6]; e67_1 = ebq[7];

    if (more)  // stage next tile into the other phase
      stage16(src + (size_t)(ti + 1) * 256, lds + ((ti + 1) & 1) * 256);

    STEPQ(0, 0, 2);  STEPQ(1, 1, 0);  STEPQ(2, 2, 1);  STEPQ(3, 0, 2);
    STEPQ(4, 1, 0);  STEPQ(5, 2, 1);  STEPQ(6, 0, 2);  STEPQ(7, 1, 0);
    STEPQ(8, 2, 1);  STEPQ(9, 0, 2);  STEPQ(10, 1, 0); STEPQ(11, 2, 1);
    STEPQ(12, 0, 2); STEPQ(13, 1, 0); STEPQ(14, 2, 1); STEPQ(15, 0, 2);
    STEPQ(16, 1, 0); STEPQ(17, 2, 1); STEPQ(18, 0, 2); STEPQ(19, 1, 0);
    STEPQ(20, 2, 1); STEPQ(21, 0, 2); STEPQ(22, 1, 0); STEPQ(23, 2, 1);
    STEPQ(24, 0, 2); STEPQ(25, 1, 0); STEPQ(26, 2, 1); STEPQ(27, 0, 2);
    STEPQ(28, 1, 0); STEPQ(29, 2, 1); STEPQ(30, 0, 2); STEPQ(31, 1, 0);

    if (more) {
      // outstanding VMEM (oldest->newest): stage(ti+1), 4 pack stores = 5;
      // in-order retirement => vmcnt(4) <=> stage(ti+1) arrived.
      asm volatile("s_waitcnt vmcnt(4)" ::: "memory");
      __builtin_amdgcn_sched_barrier(0);
    }
  }
}

// ---------------- scatter cid bytes to the per-pixel lane map ----------------
__global__ void k_scatter(const unsigned char* __restrict__ cidArr,
                          const int* __restrict__ idxC, const int* __restrict__ nvalid,
                          unsigned char* __restrict__ lanes, int cap) {
  const int b = blockIdx.y;
  const int n = nvalid[b];
  for (int j = blockIdx.x * blockDim.x + threadIdx.x; j < n; j += gridDim.x * blockDim.x) {
    lanes[(size_t)b * HW_ + idxC[(size_t)b * cap + j]] = cidArr[(size_t)b * HW_ + j];
  }
}

// ---------------- per-(b,h) segment sums over 33 lane bins ----------------
__global__ void k_rowsum(const unsigned char* __restrict__ lanes,
                         const float* __restrict__ offp, const float* __restrict__ zp,
                         float* __restrict__ cnt, float* __restrict__ sx,
                         float* __restrict__ sz) {
  const int bh = blockIdx.x;
  const int b = bh >> 9, h = bh & 511;
  __shared__ float sc[33], sxx[33], szz[33];
  const int t = threadIdx.x;
  if (t < 33) { sc[t] = 0.f; sxx[t] = 0.f; szz[t] = 0.f; }
  __syncthreads();
  const size_t base = (size_t)bh * W_;
  for (int x = t; x < W_; x += 256) {
    int ln = lanes[base + x];
    float o = offp[base + x];
    float sig = 1.0f / (1.0f + expf(-o));
    float xa = (float)x + sig;
    float zv = zp[base + x];
    atomicAdd(&sc[ln], 1.0f);
    atomicAdd(&sxx[ln], xa);
    atomicAdd(&szz[ln], zv);
  }
  __syncthreads();
  if (t >= 1 && t < 33) {
    size_t o = ((size_t)b * K_ + (t - 1)) * H_ + h;
    cnt[o] = sc[t]; sx[o] = sxx[t]; sz[o] = szz[t];
  }
}

// ---------------- validity + point assembly ----------------
__global__ void k_final(const float* __restrict__ cnt, const float* __restrict__ sx,
                        const float* __restrict__ sz, float* __restrict__ out) {
  const int bk = blockIdx.x;
  const int b = bk >> 5, k = bk & 31;
  const int h = threadIdx.x;
  const size_t o = (size_t)bk * H_ + h;
  float c = cnt[o];
  float sc_ = c, sn = (c > 0.f) ? 1.f : 0.f;
#pragma unroll
  for (int off = 32; off >= 1; off >>= 1) {
    sc_ += __shfl_down(sc_, off);
    sn += __shfl_down(sn, off);
  }
  __shared__ float rs[8], rn[8], tot[2];
  const int wid = h >> 6, lid = h & 63;
  if (lid == 0) { rs[wid] = sc_; rn[wid] = sn; }
  __syncthreads();
  if (h == 0) {
    float a = 0, bb = 0;
#pragma unroll
    for (int q = 0; q < 8; ++q) { a += rs[q]; bb += rn[q]; }
    tot[0] = a; tot[1] = bb;
  }
  __syncthreads();
  float size = tot[0], nrows = tot[1];
  bool valid = (c > 0.f) && (size >= 50.f) && (nrows >= 2.f);
  float mx = sx[o] / fmaxf(c, 1.f);
  float mz = sz[o] / fmaxf(c, 1.f);
  float xw = (512.0f - ((float)h + 0.5f)) * 0.2f;
  float yw = -(mx - 256.0f) * 0.2f;
  out[((size_t)(b * 3 + 0) * K_ + k) * H_ + h] = valid ? xw : 0.f;
  out[((size_t)(b * 3 + 1) * K_ + k) * H_ + h] = valid ? yw : 0.f;
  out[((size_t)(b * 3 + 2) * K_ + k) * H_ + h] = valid ? mz : 0.f;
  out[(size_t)B_ * 3 * K_ * H_ + (size_t)bk * H_ + h] = valid ? 1.f : 0.f;
}

extern "C" void kernel_launch(void* const* d_in, const int* in_sizes, int n_in,
                              void* d_out, int out_size, void* d_ws, size_t ws_size,
                              hipStream_t stream) {
  const float* seg  = (const float*)d_in[0];
  const float* emb  = (const float*)d_in[1];
  const float* offp = (const float*)d_in[2];
  const float* zp   = (const float*)d_in[3];
  float* out = (float*)d_out;
  char* ws = (char*)d_ws;

  const size_t lanesOff = 0;
  const size_t cntOff   = (size_t)B_ * HW_;
  const size_t sxOff    = cntOff + (size_t)B_ * K_ * H_ * 4;
  const size_t szOff    = sxOff  + (size_t)B_ * K_ * H_ * 4;
  const size_t nvOff    = szOff  + (size_t)B_ * K_ * H_ * 4;
  const size_t ccOff    = nvOff + 256;
  const size_t cbOff    = ccOff + 1024;
  const size_t cidOff   = cbOff + 1024;                      // u8 [B][HW_] = 2 MiB
  const size_t idxOff   = cidOff + (size_t)B_ * HW_;
  size_t avail = (ws_size > idxOff + 8192) ? (ws_size - idxOff - 8192) : 0;  // staging slack
  long long capLL = (long long)(avail / ((size_t)B_ * 36));  // 4B idx + 32B emb per entry
  if (capLL > (long long)HW_) capLL = HW_;
  if (capLL < 2) capLL = 2;
  capLL &= ~1LL;  // keep per-batch embC base 64B-aligned
  const int cap = (int)capLL;
  const size_t embOff = idxOff + (size_t)B_ * cap * 4;

  unsigned char* lanes = (unsigned char*)(ws + lanesOff);
  float* cnt = (float*)(ws + cntOff);
  float* sx  = (float*)(ws + sxOff);
  float* sz  = (float*)(ws + szOff);
  int* nvalid = (int*)(ws + nvOff);
  int* chunkCnt  = (int*)(ws + ccOff);
  int* chunkBase = (int*)(ws + cbOff);
  unsigned char* cidArr = (unsigned char*)(ws + cidOff);
  int* idxC   = (int*)(ws + idxOff);
  float* embC = (float*)(ws + embOff);

  k_count<<<B_ * CH_, 256, 0, stream>>>(seg, chunkCnt);
  k_scan<<<1, 128, 0, stream>>>(chunkCnt, chunkBase, nvalid, cap);
  k_fill<<<B_ * CH_, 256, 0, stream>>>(seg, emb, chunkBase, lanes, idxC, embC, cap);
  k_cluster<<<B_, 64, 0, stream>>>(embC, nvalid, cidArr, cap);
  k_scatter<<<dim3(64, B_), 256, 0, stream>>>(cidArr, idxC, nvalid, lanes, cap);
  k_rowsum<<<B_ * H_, 256, 0, stream>>>(lanes, offp, zp, cnt, sx, sz);
  k_final<<<B_ * K_, H_, 0, stream>>>(cnt, sx, sz, out);
}